// Round 1
// baseline (6141.739 us; speedup 1.0000x reference)
//
#include <hip/hip_runtime.h>
#include <math.h>

// Problem constants
#define NB 48      // batch*nodes
#define HD 256     // hidden
#define TS 512     // timesteps
// 2T-1 = 1023 relative positions

// ws layout (floats): emb[1023*256] | q[24576*256] | k[..] | v[..] | vx[24576]
// total = 19,160,832 floats = 76.7 MB

// ---------------------------------------------------------------------------
// emb_rel[r][c] = (concat(sin, cos)(rel * freqs) @ teW + teb),  rel = r - 511
// ---------------------------------------------------------------------------
__global__ __launch_bounds__(256) void k_embrel(
    const float* __restrict__ teW, const float* __restrict__ teb,
    float* __restrict__ emb)
{
  __shared__ float e[256];
  const int r = blockIdx.x;        // 0..1022
  const int tid = threadIdx.x;
  const float rel = (float)(r - (TS - 1));
  if (tid < 128) {
    float f = expf((float)tid * (-9.210340371976184f / 127.0f)); // -ln(1e4)/(half-1)
    float ang = rel * f;
    e[tid] = sinf(ang);
    e[tid + 128] = cosf(ang);
  }
  __syncthreads();
  float acc = teb[tid];
  for (int kk = 0; kk < 256; ++kk)
    acc = fmaf(e[kk], teW[kk * 256 + tid], acc);
  emb[r * 256 + tid] = acc;
}

// ---------------------------------------------------------------------------
// Fused 2-layer MLP: out = SiLU(hm @ W1 + b1) @ W2 + b2
// hm[m, c] = h[b, c, t] with m = b*T + t  (transpose fused into the A-load)
// grid (768, 3): 32-row M-tiles x {q,k,v}; 256 threads; tr=row, tc=col-block
// ---------------------------------------------------------------------------
__global__ __launch_bounds__(256) void k_mlp(
    const float* __restrict__ hin,
    const float* __restrict__ qW1, const float* __restrict__ qb1,
    const float* __restrict__ qW2, const float* __restrict__ qb2,
    const float* __restrict__ kW1, const float* __restrict__ kb1,
    const float* __restrict__ kW2, const float* __restrict__ kb2,
    const float* __restrict__ vW1, const float* __restrict__ vb1,
    const float* __restrict__ vW2, const float* __restrict__ vb2,
    float* __restrict__ qo, float* __restrict__ ko, float* __restrict__ vo)
{
  __shared__ float Ht[256 * 32];   // hidden, transposed [c][r]: broadcast reads
  const float *W1, *B1, *W2, *B2;
  float* out;
  if (blockIdx.y == 0)      { W1 = qW1; B1 = qb1; W2 = qW2; B2 = qb2; out = qo; }
  else if (blockIdx.y == 1) { W1 = kW1; B1 = kb1; W2 = kW2; B2 = kb2; out = ko; }
  else                      { W1 = vW1; B1 = vb1; W2 = vW2; B2 = vb2; out = vo; }
  const int m0 = blockIdx.x * 32;
  const int bb = m0 >> 9;          // T = 512
  const int t0 = m0 & (TS - 1);
  const int tid = threadIdx.x;
  const int tr = tid >> 3;         // 0..31 row in tile
  const int tc = tid & 7;          // 0..7  -> cols tc*32..tc*32+31
  const float* arow = hin + bb * (HD * TS) + t0 + tr;  // element kk at arow[kk*TS]

  float acc[32];
#pragma unroll
  for (int j = 0; j < 32; ++j) acc[j] = B1[tc * 32 + j];
  for (int kk = 0; kk < 256; ++kk) {
    float a = arow[kk * TS];
    const float4* w4 = (const float4*)(W1 + kk * 256 + tc * 32);
#pragma unroll
    for (int j4 = 0; j4 < 8; ++j4) {
      float4 w = w4[j4];
      acc[4*j4+0] = fmaf(a, w.x, acc[4*j4+0]);
      acc[4*j4+1] = fmaf(a, w.y, acc[4*j4+1]);
      acc[4*j4+2] = fmaf(a, w.z, acc[4*j4+2]);
      acc[4*j4+3] = fmaf(a, w.w, acc[4*j4+3]);
    }
  }
#pragma unroll
  for (int j = 0; j < 32; ++j) {
    float xx = acc[j];
    Ht[(tc * 32 + j) * 32 + tr] = xx / (1.0f + __expf(-xx));   // SiLU
  }
  __syncthreads();

#pragma unroll
  for (int j = 0; j < 32; ++j) acc[j] = B2[tc * 32 + j];
  for (int kk = 0; kk < 256; ++kk) {
    float a = Ht[kk * 32 + tr];    // 8 banks, broadcast within groups
    const float4* w4 = (const float4*)(W2 + kk * 256 + tc * 32);
#pragma unroll
    for (int j4 = 0; j4 < 8; ++j4) {
      float4 w = w4[j4];
      acc[4*j4+0] = fmaf(a, w.x, acc[4*j4+0]);
      acc[4*j4+1] = fmaf(a, w.y, acc[4*j4+1]);
      acc[4*j4+2] = fmaf(a, w.z, acc[4*j4+2]);
      acc[4*j4+3] = fmaf(a, w.w, acc[4*j4+3]);
    }
  }
  float4* o4 = (float4*)(out + (m0 + tr) * 256 + tc * 32);
#pragma unroll
  for (int j4 = 0; j4 < 8; ++j4)
    o4[j4] = make_float4(acc[4*j4], acc[4*j4+1], acc[4*j4+2], acc[4*j4+3]);
}

// ---------------------------------------------------------------------------
// v_x[m] = SiLU(v[m,:] @ xW1 + xb1) @ xW2 + xb2   (hidden kept in registers)
// ---------------------------------------------------------------------------
__global__ __launch_bounds__(256) void k_vx(
    const float* __restrict__ vin,
    const float* __restrict__ xW1, const float* __restrict__ xb1,
    const float* __restrict__ xW2, const float* __restrict__ xb2,
    float* __restrict__ vx)
{
  const int m0 = blockIdx.x * 32;
  const int tid = threadIdx.x;
  const int tr = tid >> 3, tc = tid & 7;
  const float* vrow = vin + (m0 + tr) * 256;

  float acc[32];
#pragma unroll
  for (int j = 0; j < 32; ++j) acc[j] = xb1[tc * 32 + j];
  for (int kk = 0; kk < 256; ++kk) {
    float a = vrow[kk];
    const float4* w4 = (const float4*)(xW1 + kk * 256 + tc * 32);
#pragma unroll
    for (int j4 = 0; j4 < 8; ++j4) {
      float4 w = w4[j4];
      acc[4*j4+0] = fmaf(a, w.x, acc[4*j4+0]);
      acc[4*j4+1] = fmaf(a, w.y, acc[4*j4+1]);
      acc[4*j4+2] = fmaf(a, w.z, acc[4*j4+2]);
      acc[4*j4+3] = fmaf(a, w.w, acc[4*j4+3]);
    }
  }
  float p = 0.0f;
#pragma unroll
  for (int j = 0; j < 32; ++j) {
    float xx = acc[j];
    p = fmaf(xx / (1.0f + __expf(-xx)), xW2[tc * 32 + j], p);
  }
  p += __shfl_xor(p, 1);
  p += __shfl_xor(p, 2);
  p += __shfl_xor(p, 4);
  if (tc == 0) vx[m0 + tr] = p + xb2[0];
}

// ---------------------------------------------------------------------------
// Fused attention per (b, 16-row t-tile):
//   logits[t][s] = q.k + q.emb_rel[t-s+511]  -> softmax -> alpha
//   h_new[b,h,t] = h + sum_s alpha*v[s,h] + sum_s alpha*emb_rel[t-s+511,h]
//   x_new[b,c,t] = x + x*sum_s w - sum_s w*x[c,s],  w = alpha*vx[s]
// LDS: buf[31][260] staging (K/V/E-band/out-transpose), L[16][516] logits/alpha
// ---------------------------------------------------------------------------
__global__ __launch_bounds__(256) void k_attn(
    const float* __restrict__ xin, const float* __restrict__ hin,
    const float* __restrict__ qm, const float* __restrict__ km,
    const float* __restrict__ vm, const float* __restrict__ vxm,
    const float* __restrict__ emb,
    float* __restrict__ xout, float* __restrict__ hout)
{
  __shared__ float buf[31 * 260];  // 32.2 KB
  __shared__ float L[16 * 516];    // 33.0 KB  (logits -> alpha, in place)
  const int t0 = blockIdx.x * 16;
  const int b  = blockIdx.y;
  const int tid = threadIdx.x;
  const int ty = tid >> 4;         // 0..15 t-row
  const int tx = tid & 15;         // 0..15 s-lane / col-lane
  const float* qrow = qm + (b * TS + t0 + ty) * 256;   // L1-resident, broadcast

  // ---- phase 1a: logits = Q . K^T, K-tiles staged in LDS ----
  for (int st = 0; st < 32; ++st) {
    const int s0 = st * 16;
    __syncthreads();                                   // buf free from prev use
    {
      const float* ksrc = km + (b * TS + s0 + ty) * 256;
#pragma unroll
      for (int jj = 0; jj < 4; ++jj) {
        int c4 = (tx + 16 * jj) * 4;
        *(float4*)&buf[ty * 260 + c4] = *(const float4*)&ksrc[c4];
      }
    }
    __syncthreads();
    float a = 0.0f;
    const float* kp = &buf[tx * 260];
    for (int kk = 0; kk < 256; kk += 4) {
      float4 qv = *(const float4*)&qrow[kk];
      float4 kv = *(const float4*)&kp[kk];
      a = fmaf(qv.x, kv.x, a); a = fmaf(qv.y, kv.y, a);
      a = fmaf(qv.z, kv.z, a); a = fmaf(qv.w, kv.w, a);
    }
    L[ty * 516 + s0 + tx] = a;
  }

  // ---- phase 1b: logits += Q . emb_rel[t-s+511]^T, 31-row band staged ----
  for (int st = 0; st < 32; ++st) {
    const int s0 = st * 16;
    const int rbase = t0 - s0 + 496;                   // band start (always valid)
    __syncthreads();
    for (int rr = ty; rr < 31; rr += 16) {
      const float* esrc = emb + (rbase + rr) * 256;
#pragma unroll
      for (int jj = 0; jj < 4; ++jj) {
        int c4 = (tx + 16 * jj) * 4;
        *(float4*)&buf[rr * 260 + c4] = *(const float4*)&esrc[c4];
      }
    }
    __syncthreads();
    float a = 0.0f;
    const float* ep = &buf[(ty - tx + 15) * 260];      // r = rbase + (ty-tx+15)
    for (int kk = 0; kk < 256; kk += 4) {
      float4 qv = *(const float4*)&qrow[kk];
      float4 ev = *(const float4*)&ep[kk];
      a = fmaf(qv.x, ev.x, a); a = fmaf(qv.y, ev.y, a);
      a = fmaf(qv.z, ev.z, a); a = fmaf(qv.w, ev.w, a);
    }
    L[ty * 516 + s0 + tx] += a;
  }

  // ---- softmax over s (each thread owns s = tx + 16j of its row ty) ----
  float lv[32];
#pragma unroll
  for (int j = 0; j < 32; ++j) lv[j] = L[ty * 516 + 16 * j + tx];
  float mx = lv[0];
#pragma unroll
  for (int j = 1; j < 32; ++j) mx = fmaxf(mx, lv[j]);
  for (int msk = 1; msk < 16; msk <<= 1) mx = fmaxf(mx, __shfl_xor(mx, msk));
  float ssum = 0.0f;
#pragma unroll
  for (int j = 0; j < 32; ++j) { lv[j] = __expf(lv[j] - mx); ssum += lv[j]; }
  for (int msk = 1; msk < 16; msk <<= 1) ssum += __shfl_xor(ssum, msk);
  const float inv = 1.0f / ssum;
#pragma unroll
  for (int j = 0; j < 32; ++j) lv[j] *= inv;           // alpha

  // ---- equivariant x update (uses register alphas) ----
  {
    float wsum = 0.f, xa0 = 0.f, xa1 = 0.f, xa2 = 0.f;
    const float* vxb = vxm + b * TS;
    const float* xbase = xin + b * 3 * TS;
#pragma unroll
    for (int j = 0; j < 32; ++j) {
      int s = 16 * j + tx;
      float wv = lv[j] * vxb[s];
      wsum += wv;
      xa0 = fmaf(wv, xbase[s], xa0);
      xa1 = fmaf(wv, xbase[TS + s], xa1);
      xa2 = fmaf(wv, xbase[2 * TS + s], xa2);
    }
    for (int msk = 1; msk < 16; msk <<= 1) {
      wsum += __shfl_xor(wsum, msk);
      xa0  += __shfl_xor(xa0, msk);
      xa1  += __shfl_xor(xa1, msk);
      xa2  += __shfl_xor(xa2, msk);
    }
    if (tx == 0) {
      int t = t0 + ty;
      xout[(b * 3 + 0) * TS + t] = xbase[t]          * (1.0f + wsum) - xa0;
      xout[(b * 3 + 1) * TS + t] = xbase[TS + t]     * (1.0f + wsum) - xa1;
      xout[(b * 3 + 2) * TS + t] = xbase[2 * TS + t] * (1.0f + wsum) - xa2;
    }
  }

  // ---- store alpha back to LDS for the contraction phases ----
#pragma unroll
  for (int j = 0; j < 32; ++j) L[ty * 516 + 16 * j + tx] = lv[j];

  float sa[16], ba[16];
#pragma unroll
  for (int c = 0; c < 16; ++c) { sa[c] = 0.f; ba[c] = 0.f; }

  // ---- phase 2a: std_vs[t][h] = sum_s alpha * V[s][h] ----
  for (int st = 0; st < 32; ++st) {
    const int s0 = st * 16;
    __syncthreads();                                   // also covers alpha stores
    {
      const float* vsrc = vm + (b * TS + s0 + ty) * 256;
#pragma unroll
      for (int jj = 0; jj < 4; ++jj) {
        int c4 = (tx + 16 * jj) * 4;
        *(float4*)&buf[ty * 260 + c4] = *(const float4*)&vsrc[c4];
      }
    }
    __syncthreads();
#pragma unroll
    for (int ss = 0; ss < 16; ++ss) {
      float a = L[ty * 516 + s0 + ss];                 // broadcast
      const float* vp = &buf[ss * 260 + tx];
#pragma unroll
      for (int c = 0; c < 16; ++c)
        sa[c] = fmaf(a, vp[16 * c], sa[c]);            // h-col = tx + 16c
    }
  }

  // ---- phase 2b: bias_h[t][h] = sum_s alpha * emb_rel[t-s+511][h] ----
  for (int st = 0; st < 32; ++st) {
    const int s0 = st * 16;
    const int rbase = t0 - s0 + 496;
    __syncthreads();
    for (int rr = ty; rr < 31; rr += 16) {
      const float* esrc = emb + (rbase + rr) * 256;
#pragma unroll
      for (int jj = 0; jj < 4; ++jj) {
        int c4 = (tx + 16 * jj) * 4;
        *(float4*)&buf[rr * 260 + c4] = *(const float4*)&esrc[c4];
      }
    }
    __syncthreads();
#pragma unroll
    for (int ss = 0; ss < 16; ++ss) {
      float a = L[ty * 516 + s0 + ss];
      const float* ep = &buf[(ty - ss + 15) * 260 + tx];
#pragma unroll
      for (int c = 0; c < 16; ++c)
        ba[c] = fmaf(a, ep[16 * c], ba[c]);
    }
  }

  // ---- transpose through LDS, then 64B-granular h_new writes ----
  __syncthreads();
#pragma unroll
  for (int c = 0; c < 16; ++c)
    buf[ty * 260 + tx + 16 * c] = sa[c] + ba[c];       // [t-row][h-col]
  __syncthreads();
  {
    const int hh = tid;                                // 0..255 h-row
    const float* hrow = hin + (b * 256 + hh) * TS + t0;
    float* orow = hout + (b * 256 + hh) * TS + t0;
#pragma unroll
    for (int i = 0; i < 4; ++i) {
      float4 hv = *(const float4*)&hrow[4 * i];
      float4 ov;
      ov.x = hv.x + buf[(4 * i + 0) * 260 + hh];
      ov.y = hv.y + buf[(4 * i + 1) * 260 + hh];
      ov.z = hv.z + buf[(4 * i + 2) * 260 + hh];
      ov.w = hv.w + buf[(4 * i + 3) * 260 + hh];
      *(float4*)&orow[4 * i] = ov;
    }
  }
}

// ---------------------------------------------------------------------------
extern "C" void kernel_launch(void* const* d_in, const int* in_sizes, int n_in,
                              void* d_out, int out_size, void* d_ws, size_t ws_size,
                              hipStream_t stream)
{
  const float* x   = (const float*)d_in[0];
  const float* h   = (const float*)d_in[1];
  const float* qW1 = (const float*)d_in[2];
  const float* qb1 = (const float*)d_in[3];
  const float* qW2 = (const float*)d_in[4];
  const float* qb2 = (const float*)d_in[5];
  const float* kW1 = (const float*)d_in[6];
  const float* kb1 = (const float*)d_in[7];
  const float* kW2 = (const float*)d_in[8];
  const float* kb2 = (const float*)d_in[9];
  const float* vW1 = (const float*)d_in[10];
  const float* vb1 = (const float*)d_in[11];
  const float* vW2 = (const float*)d_in[12];
  const float* vb2 = (const float*)d_in[13];
  const float* xW1 = (const float*)d_in[14];
  const float* xb1 = (const float*)d_in[15];
  const float* xW2 = (const float*)d_in[16];
  const float* xb2 = (const float*)d_in[17];
  const float* teW = (const float*)d_in[18];
  const float* teb = (const float*)d_in[19];

  float* ws  = (float*)d_ws;                 // needs 76.7 MB
  float* emb = ws;                           // 1023*256
  float* q   = emb + 1023 * 256;             // 24576*256
  float* k   = q + 24576 * 256;
  float* v   = k + 24576 * 256;
  float* vx  = v + 24576 * 256;              // 24576

  float* xout = (float*)d_out;               // [48,3,512]
  float* hout = xout + NB * 3 * TS;          // [48,256,512]

  k_embrel<<<1023, 256, 0, stream>>>(teW, teb, emb);
  k_mlp<<<dim3(768, 3), 256, 0, stream>>>(h, qW1, qb1, qW2, qb2,
                                          kW1, kb1, kW2, kb2,
                                          vW1, vb1, vW2, vb2, q, k, v);
  k_vx<<<768, 256, 0, stream>>>(v, xW1, xb1, xW2, xb2, vx);
  k_attn<<<dim3(32, 48), 256, 0, stream>>>(x, h, q, k, v, vx, emb, xout, hout);
}

// Round 2
// 1460.105 us; speedup vs baseline: 4.2064x; 4.2064x over previous
//
#include <hip/hip_runtime.h>
#include <math.h>

// Problem constants
#define NB 48      // batch*nodes
#define HD 256     // hidden
#define TS 512     // timesteps
// 2T-1 = 1023 relative positions

typedef __bf16 bf16x8 __attribute__((ext_vector_type(8)));
typedef float  f32x4  __attribute__((ext_vector_type(4)));

__device__ inline unsigned short f2b(float f) {       // f32 -> bf16 bits, RNE
  union { float f; unsigned u; } v; v.f = f;
  unsigned r = v.u + 0x7fff + ((v.u >> 16) & 1);
  return (unsigned short)(r >> 16);
}
__device__ inline float b2f(unsigned short u) {
  union { unsigned u; float f; } v; v.u = ((unsigned)u) << 16;
  return v.f;
}

// ---------------------------------------------------------------------------
// emb_rel[r][c] = (concat(sin, cos)(rel * freqs) @ teW + teb),  rel = r - 511
// ---------------------------------------------------------------------------
__global__ __launch_bounds__(256) void k_embrel(
    const float* __restrict__ teW, const float* __restrict__ teb,
    float* __restrict__ emb)
{
  __shared__ float e[256];
  const int r = blockIdx.x;        // 0..1022
  const int tid = threadIdx.x;
  const float rel = (float)(r - (TS - 1));
  if (tid < 128) {
    float f = expf((float)tid * (-9.210340371976184f / 127.0f)); // -ln(1e4)/(half-1)
    float ang = rel * f;
    e[tid] = sinf(ang);
    e[tid + 128] = cosf(ang);
  }
  __syncthreads();
  float acc = teb[tid];
  for (int kk = 0; kk < 256; ++kk)
    acc = fmaf(e[kk], teW[kk * 256 + tid], acc);
  emb[r * 256 + tid] = acc;
}

// ---------------------------------------------------------------------------
// h [48,256,512] fp32  ->  hmB [24576][256] bf16   (hm[m,c] = h[b,c,t])
// grid (4 t-tiles, 8 c-tiles, 48 b); LDS tile [32 c][128 t]
// ---------------------------------------------------------------------------
__global__ __launch_bounds__(256) void k_prep_h(
    const float* __restrict__ h, unsigned short* __restrict__ hmB)
{
  __shared__ float t[32 * 132];
  const int t0 = blockIdx.x * 128, c0 = blockIdx.y * 32, b = blockIdx.z;
  const int tid = threadIdx.x;
#pragma unroll
  for (int i = 0; i < 4; ++i) {
    int cl = i * 8 + (tid >> 5);           // 0..31
    int t4 = (tid & 31) * 4;               // 0..124
    float4 v = *(const float4*)&h[((size_t)b * 256 + c0 + cl) * 512 + t0 + t4];
    t[cl * 132 + t4 + 0] = v.x; t[cl * 132 + t4 + 1] = v.y;
    t[cl * 132 + t4 + 2] = v.z; t[cl * 132 + t4 + 3] = v.w;
  }
  __syncthreads();
#pragma unroll
  for (int i = 0; i < 16; ++i) {
    int tl = i * 8 + (tid >> 5);           // 0..127
    int cl = tid & 31;
    hmB[((size_t)b * 512 + t0 + tl) * 256 + c0 + cl] = f2b(t[cl * 132 + tl]);
  }
}

// ---------------------------------------------------------------------------
// Weights fp32 [K=256][N=256] -> bf16 transposed [N][K], 7 matrices
// grid (4 k-tiles, 4 n-tiles, 7 mats); LDS 64x64 tile
// ---------------------------------------------------------------------------
__global__ __launch_bounds__(256) void k_prep_w(
    const float* __restrict__ w0, const float* __restrict__ w1,
    const float* __restrict__ w2, const float* __restrict__ w3,
    const float* __restrict__ w4, const float* __restrict__ w5,
    const float* __restrict__ w6, unsigned short* __restrict__ WtB)
{
  __shared__ float t[64 * 68];
  const int mat = blockIdx.z;
  const float* W = (mat == 0) ? w0 : (mat == 1) ? w1 : (mat == 2) ? w2 :
                   (mat == 3) ? w3 : (mat == 4) ? w4 : (mat == 5) ? w5 : w6;
  unsigned short* dst = WtB + (size_t)mat * 65536;
  const int k0 = blockIdx.x * 64, n0 = blockIdx.y * 64;
  const int tid = threadIdx.x;
#pragma unroll
  for (int i = 0; i < 4; ++i) {
    int kr = i * 16 + (tid >> 4);          // 0..63 local k
    int nc = (tid & 15) * 4;               // 0..60 local n
    float4 v = *(const float4*)&W[(size_t)(k0 + kr) * 256 + n0 + nc];
    t[kr * 68 + nc + 0] = v.x; t[kr * 68 + nc + 1] = v.y;
    t[kr * 68 + nc + 2] = v.z; t[kr * 68 + nc + 3] = v.w;
  }
  __syncthreads();
#pragma unroll
  for (int i = 0; i < 4; ++i) {
    int nr = i * 16 + (tid >> 4);          // local n
    int kc = (tid & 15) * 4;               // local k
#pragma unroll
    for (int j = 0; j < 4; ++j)
      dst[(size_t)(n0 + nr) * 256 + k0 + kc + j] = f2b(t[(kc + j) * 68 + nr]);
  }
}

// ---------------------------------------------------------------------------
// bf16 MFMA GEMM: C[M,256] = act(A[M,256] @ Wt^T + bias)
//   A bf16 [M][256] row-major; Wt bf16 [256(N)][256(K)] row-major (=W^T)
//   BM=128, BN=128, BK=128 (2 K-steps), 4 waves in 2x2, 64x64 per wave
//   LDS: As/Ws 32KB each, XOR-swizzled 16B chunks (T2) for conflict-free
//   ds_read_b128.  ACT: 0=none, 1=SiLU.  outF (fp32) / outB (bf16) optional.
// ---------------------------------------------------------------------------
template<int ACT>
__global__ __launch_bounds__(256) void k_gemm(
    const unsigned short* __restrict__ A, const unsigned short* __restrict__ Wt,
    const float* __restrict__ bias,
    float* __restrict__ outF, unsigned short* __restrict__ outB)
{
  __shared__ uint4 As4[2048];   // 32 KB
  __shared__ uint4 Ws4[2048];   // 32 KB
  char* AsB = (char*)As4;
  char* WsB = (char*)Ws4;

  const int tid  = threadIdx.x;
  const int lane = tid & 63;
  const int w    = tid >> 6;
  const int wr   = w >> 1, wc = w & 1;     // wave grid 2x2
  const int rq   = lane & 15;              // row-in-fragment / out-col
  const int kq   = lane >> 4;              // k-slice quarter (0..3)

  const int m0 = blockIdx.x * 128;
  const int n0 = blockIdx.y * 128;
  const char* Ag = (const char*)A  + (size_t)m0 * 512;   // 512 B per row (256 bf16)
  const char* Wg = (const char*)Wt + (size_t)n0 * 512;

  f32x4 acc[4][4];
#pragma unroll
  for (int mi = 0; mi < 4; ++mi)
#pragma unroll
    for (int ni = 0; ni < 4; ++ni)
      acc[mi][ni] = (f32x4){0.f, 0.f, 0.f, 0.f};

  for (int kt = 0; kt < 2; ++kt) {
    __syncthreads();
    // stage A-tile and W-tile (each 128 rows x 256 B), swizzled 16B chunks
#pragma unroll
    for (int i = 0; i < 8; ++i) {
      int c = i * 256 + tid;               // chunk 0..2047
      int row = c >> 4;                    // 16 chunks per row
      int colb = (c & 15) * 16;
      int sw = colb ^ ((row & 7) << 4);
      *(uint4*)(AsB + row * 256 + sw) =
          *(const uint4*)(Ag + (size_t)row * 512 + kt * 256 + colb);
      *(uint4*)(WsB + row * 256 + sw) =
          *(const uint4*)(Wg + (size_t)row * 512 + kt * 256 + colb);
    }
    __syncthreads();

#pragma unroll
    for (int kk = 0; kk < 4; ++kk) {       // 4 x K=32 within BK=128
      const int kb = kk * 64 + kq * 16;    // byte col of this lane's 8 bf16
      bf16x8 af[4], bfr[4];
#pragma unroll
      for (int mi = 0; mi < 4; ++mi) {
        int row = wr * 64 + mi * 16 + rq;
        af[mi] = *(const bf16x8*)(AsB + row * 256 + (kb ^ ((row & 7) << 4)));
      }
#pragma unroll
      for (int ni = 0; ni < 4; ++ni) {
        int row = wc * 64 + ni * 16 + rq;
        bfr[ni] = *(const bf16x8*)(WsB + row * 256 + (kb ^ ((row & 7) << 4)));
      }
#pragma unroll
      for (int mi = 0; mi < 4; ++mi)
#pragma unroll
        for (int ni = 0; ni < 4; ++ni)
          acc[mi][ni] = __builtin_amdgcn_mfma_f32_16x16x32_bf16(
              af[mi], bfr[ni], acc[mi][ni], 0, 0, 0);
    }
  }

  // epilogue: bias + optional SiLU; C/D layout col=lane&15, row=(lane>>4)*4+reg
  float bv[4];
#pragma unroll
  for (int ni = 0; ni < 4; ++ni)
    bv[ni] = bias[n0 + wc * 64 + ni * 16 + rq];

#pragma unroll
  for (int mi = 0; mi < 4; ++mi) {
#pragma unroll
    for (int ni = 0; ni < 4; ++ni) {
      const int n = n0 + wc * 64 + ni * 16 + rq;
#pragma unroll
      for (int j = 0; j < 4; ++j) {
        const int m = m0 + wr * 64 + mi * 16 + kq * 4 + j;
        float vl = acc[mi][ni][j] + bv[ni];
        if (ACT) vl = vl / (1.0f + __expf(-vl));
        if (outF) outF[(size_t)m * 256 + n] = vl;
        if (outB) outB[(size_t)m * 256 + n] = f2b(vl);
      }
    }
  }
}

// ---------------------------------------------------------------------------
// vx[m] = hidX[m,:] (bf16) @ xW2 + xb2   (matvec, 32 rows per block)
// ---------------------------------------------------------------------------
__global__ __launch_bounds__(256) void k_vx2(
    const unsigned short* __restrict__ hid,
    const float* __restrict__ xW2, const float* __restrict__ xb2,
    float* __restrict__ vx)
{
  const int m0 = blockIdx.x * 32;
  const int tid = threadIdx.x;
  const int tr = tid >> 3, tc = tid & 7;
  const unsigned short* row = hid + (size_t)(m0 + tr) * 256 + tc * 32;
  float acc = 0.0f;
#pragma unroll
  for (int i = 0; i < 4; ++i) {
    uint4 r = *(const uint4*)&row[i * 8];
    const unsigned rr[4] = {r.x, r.y, r.z, r.w};
#pragma unroll
    for (int jj = 0; jj < 4; ++jj) {
      float lo = b2f((unsigned short)(rr[jj] & 0xffff));
      float hi = b2f((unsigned short)(rr[jj] >> 16));
      acc = fmaf(lo, xW2[tc * 32 + i * 8 + 2 * jj + 0], acc);
      acc = fmaf(hi, xW2[tc * 32 + i * 8 + 2 * jj + 1], acc);
    }
  }
  acc += __shfl_xor(acc, 1);
  acc += __shfl_xor(acc, 2);
  acc += __shfl_xor(acc, 4);
  if (tc == 0) vx[m0 + tr] = acc + xb2[0];
}

// ---------------------------------------------------------------------------
// Fused attention per (b, 16-row t-tile)  [unchanged from round 1]
// ---------------------------------------------------------------------------
__global__ __launch_bounds__(256) void k_attn(
    const float* __restrict__ xin, const float* __restrict__ hin,
    const float* __restrict__ qm, const float* __restrict__ km,
    const float* __restrict__ vm, const float* __restrict__ vxm,
    const float* __restrict__ emb,
    float* __restrict__ xout, float* __restrict__ hout)
{
  __shared__ float buf[31 * 260];  // 32.2 KB
  __shared__ float L[16 * 516];    // 33.0 KB  (logits -> alpha, in place)
  const int t0 = blockIdx.x * 16;
  const int b  = blockIdx.y;
  const int tid = threadIdx.x;
  const int ty = tid >> 4;         // 0..15 t-row
  const int tx = tid & 15;         // 0..15 s-lane / col-lane
  const float* qrow = qm + (b * TS + t0 + ty) * 256;

  // ---- phase 1a: logits = Q . K^T, K-tiles staged in LDS ----
  for (int st = 0; st < 32; ++st) {
    const int s0 = st * 16;
    __syncthreads();
    {
      const float* ksrc = km + (b * TS + s0 + ty) * 256;
#pragma unroll
      for (int jj = 0; jj < 4; ++jj) {
        int c4 = (tx + 16 * jj) * 4;
        *(float4*)&buf[ty * 260 + c4] = *(const float4*)&ksrc[c4];
      }
    }
    __syncthreads();
    float a = 0.0f;
    const float* kp = &buf[tx * 260];
    for (int kk = 0; kk < 256; kk += 4) {
      float4 qv = *(const float4*)&qrow[kk];
      float4 kv = *(const float4*)&kp[kk];
      a = fmaf(qv.x, kv.x, a); a = fmaf(qv.y, kv.y, a);
      a = fmaf(qv.z, kv.z, a); a = fmaf(qv.w, kv.w, a);
    }
    L[ty * 516 + s0 + tx] = a;
  }

  // ---- phase 1b: logits += Q . emb_rel[t-s+511]^T, 31-row band staged ----
  for (int st = 0; st < 32; ++st) {
    const int s0 = st * 16;
    const int rbase = t0 - s0 + 496;
    __syncthreads();
    for (int rr = ty; rr < 31; rr += 16) {
      const float* esrc = emb + (rbase + rr) * 256;
#pragma unroll
      for (int jj = 0; jj < 4; ++jj) {
        int c4 = (tx + 16 * jj) * 4;
        *(float4*)&buf[rr * 260 + c4] = *(const float4*)&esrc[c4];
      }
    }
    __syncthreads();
    float a = 0.0f;
    const float* ep = &buf[(ty - tx + 15) * 260];
    for (int kk = 0; kk < 256; kk += 4) {
      float4 qv = *(const float4*)&qrow[kk];
      float4 ev = *(const float4*)&ep[kk];
      a = fmaf(qv.x, ev.x, a); a = fmaf(qv.y, ev.y, a);
      a = fmaf(qv.z, ev.z, a); a = fmaf(qv.w, ev.w, a);
    }
    L[ty * 516 + s0 + tx] += a;
  }

  // ---- softmax over s ----
  float lv[32];
#pragma unroll
  for (int j = 0; j < 32; ++j) lv[j] = L[ty * 516 + 16 * j + tx];
  float mx = lv[0];
#pragma unroll
  for (int j = 1; j < 32; ++j) mx = fmaxf(mx, lv[j]);
  for (int msk = 1; msk < 16; msk <<= 1) mx = fmaxf(mx, __shfl_xor(mx, msk));
  float ssum = 0.0f;
#pragma unroll
  for (int j = 0; j < 32; ++j) { lv[j] = __expf(lv[j] - mx); ssum += lv[j]; }
  for (int msk = 1; msk < 16; msk <<= 1) ssum += __shfl_xor(ssum, msk);
  const float inv = 1.0f / ssum;
#pragma unroll
  for (int j = 0; j < 32; ++j) lv[j] *= inv;

  // ---- equivariant x update ----
  {
    float wsum = 0.f, xa0 = 0.f, xa1 = 0.f, xa2 = 0.f;
    const float* vxb = vxm + b * TS;
    const float* xbase = xin + b * 3 * TS;
#pragma unroll
    for (int j = 0; j < 32; ++j) {
      int s = 16 * j + tx;
      float wv = lv[j] * vxb[s];
      wsum += wv;
      xa0 = fmaf(wv, xbase[s], xa0);
      xa1 = fmaf(wv, xbase[TS + s], xa1);
      xa2 = fmaf(wv, xbase[2 * TS + s], xa2);
    }
    for (int msk = 1; msk < 16; msk <<= 1) {
      wsum += __shfl_xor(wsum, msk);
      xa0  += __shfl_xor(xa0, msk);
      xa1  += __shfl_xor(xa1, msk);
      xa2  += __shfl_xor(xa2, msk);
    }
    if (tx == 0) {
      int t = t0 + ty;
      xout[(b * 3 + 0) * TS + t] = xbase[t]          * (1.0f + wsum) - xa0;
      xout[(b * 3 + 1) * TS + t] = xbase[TS + t]     * (1.0f + wsum) - xa1;
      xout[(b * 3 + 2) * TS + t] = xbase[2 * TS + t] * (1.0f + wsum) - xa2;
    }
  }

  // ---- store alpha back to LDS ----
#pragma unroll
  for (int j = 0; j < 32; ++j) L[ty * 516 + 16 * j + tx] = lv[j];

  float sa[16], ba[16];
#pragma unroll
  for (int c = 0; c < 16; ++c) { sa[c] = 0.f; ba[c] = 0.f; }

  // ---- phase 2a: std_vs ----
  for (int st = 0; st < 32; ++st) {
    const int s0 = st * 16;
    __syncthreads();
    {
      const float* vsrc = vm + (b * TS + s0 + ty) * 256;
#pragma unroll
      for (int jj = 0; jj < 4; ++jj) {
        int c4 = (tx + 16 * jj) * 4;
        *(float4*)&buf[ty * 260 + c4] = *(const float4*)&vsrc[c4];
      }
    }
    __syncthreads();
#pragma unroll
    for (int ss = 0; ss < 16; ++ss) {
      float a = L[ty * 516 + s0 + ss];
      const float* vp = &buf[ss * 260 + tx];
#pragma unroll
      for (int c = 0; c < 16; ++c)
        sa[c] = fmaf(a, vp[16 * c], sa[c]);
    }
  }

  // ---- phase 2b: bias_h ----
  for (int st = 0; st < 32; ++st) {
    const int s0 = st * 16;
    const int rbase = t0 - s0 + 496;
    __syncthreads();
    for (int rr = ty; rr < 31; rr += 16) {
      const float* esrc = emb + (rbase + rr) * 256;
#pragma unroll
      for (int jj = 0; jj < 4; ++jj) {
        int c4 = (tx + 16 * jj) * 4;
        *(float4*)&buf[rr * 260 + c4] = *(const float4*)&esrc[c4];
      }
    }
    __syncthreads();
#pragma unroll
    for (int ss = 0; ss < 16; ++ss) {
      float a = L[ty * 516 + s0 + ss];
      const float* ep = &buf[(ty - ss + 15) * 260 + tx];
#pragma unroll
      for (int c = 0; c < 16; ++c)
        ba[c] = fmaf(a, ep[16 * c], ba[c]);
    }
  }

  // ---- transpose through LDS, then h_new writes ----
  __syncthreads();
#pragma unroll
  for (int c = 0; c < 16; ++c)
    buf[ty * 260 + tx + 16 * c] = sa[c] + ba[c];
  __syncthreads();
  {
    const int hh = tid;
    const float* hrow = hin + ((size_t)b * 256 + hh) * TS + t0;
    float* orow = hout + ((size_t)b * 256 + hh) * TS + t0;
#pragma unroll
    for (int i = 0; i < 4; ++i) {
      float4 hv = *(const float4*)&hrow[4 * i];
      float4 ov;
      ov.x = hv.x + buf[(4 * i + 0) * 260 + hh];
      ov.y = hv.y + buf[(4 * i + 1) * 260 + hh];
      ov.z = hv.z + buf[(4 * i + 2) * 260 + hh];
      ov.w = hv.w + buf[(4 * i + 3) * 260 + hh];
      *(float4*)&orow[4 * i] = ov;
    }
  }
}

// ---------------------------------------------------------------------------
extern "C" void kernel_launch(void* const* d_in, const int* in_sizes, int n_in,
                              void* d_out, int out_size, void* d_ws, size_t ws_size,
                              hipStream_t stream)
{
  const float* x   = (const float*)d_in[0];
  const float* h   = (const float*)d_in[1];
  const float* qW1 = (const float*)d_in[2];
  const float* qb1 = (const float*)d_in[3];
  const float* qW2 = (const float*)d_in[4];
  const float* qb2 = (const float*)d_in[5];
  const float* kW1 = (const float*)d_in[6];
  const float* kb1 = (const float*)d_in[7];
  const float* kW2 = (const float*)d_in[8];
  const float* kb2 = (const float*)d_in[9];
  const float* vW1 = (const float*)d_in[10];
  const float* vb1 = (const float*)d_in[11];
  const float* vW2 = (const float*)d_in[12];
  const float* vb2 = (const float*)d_in[13];
  const float* xW1 = (const float*)d_in[14];
  const float* xb1 = (const float*)d_in[15];
  const float* xW2 = (const float*)d_in[16];
  const float* xb2 = (const float*)d_in[17];
  const float* teW = (const float*)d_in[18];
  const float* teb = (const float*)d_in[19];

  // ws layout: fp32: emb | q | k | v | vx   then bf16: hmB | Wt[7] | hid | vB
  float* ws  = (float*)d_ws;
  float* emb = ws;                            // 1023*256
  float* q   = emb + 1023 * 256;              // 24576*256 each
  float* k   = q + 24576 * 256;
  float* v   = k + 24576 * 256;
  float* vx  = v + 24576 * 256;               // 24576
  unsigned short* hmB = (unsigned short*)(vx + 24576);
  unsigned short* WtB = hmB + (size_t)24576 * 256;   // 7 x 65536
  unsigned short* hid = WtB + 7 * 65536;
  unsigned short* vB  = hid + (size_t)24576 * 256;
  // total = 76.6 MB fp32 + 38.7 MB bf16 = 115.3 MB

  float* xout = (float*)d_out;                // [48,3,512]
  float* hout = xout + NB * 3 * TS;           // [48,256,512]

  k_embrel<<<1023, 256, 0, stream>>>(teW, teb, emb);
  k_prep_h<<<dim3(4, 8, 48), 256, 0, stream>>>(h, hmB);
  k_prep_w<<<dim3(4, 4, 7), 256, 0, stream>>>(qW1, qW2, kW1, kW2, vW1, vW2, xW1, WtB);

  const dim3 gg(192, 2);
  // q
  k_gemm<1><<<gg, 256, 0, stream>>>(hmB, WtB + 0 * 65536, qb1, nullptr, hid);
  k_gemm<0><<<gg, 256, 0, stream>>>(hid, WtB + 1 * 65536, qb2, q, nullptr);
  // k
  k_gemm<1><<<gg, 256, 0, stream>>>(hmB, WtB + 2 * 65536, kb1, nullptr, hid);
  k_gemm<0><<<gg, 256, 0, stream>>>(hid, WtB + 3 * 65536, kb2, k, nullptr);
  // v (also bf16 copy for the x-MLP)
  k_gemm<1><<<gg, 256, 0, stream>>>(hmB, WtB + 4 * 65536, vb1, nullptr, hid);
  k_gemm<0><<<gg, 256, 0, stream>>>(hid, WtB + 5 * 65536, vb2, v, vB);
  // x-MLP layer 1 (input = v), then matvec layer 2
  k_gemm<1><<<gg, 256, 0, stream>>>(vB, WtB + 6 * 65536, xb1, nullptr, hid);
  k_vx2<<<768, 256, 0, stream>>>(hid, xW2, xb2, vx);

  k_attn<<<dim3(32, 48), 256, 0, stream>>>(x, h, q, k, v, vx, emb, xout, hout);
}

// Round 4
// 421.877 us; speedup vs baseline: 14.5581x; 3.4610x over previous
//
#include <hip/hip_runtime.h>
#include <math.h>

// Problem constants
#define NB 48      // batch*nodes
#define HD 256     // hidden
#define TS 512     // timesteps
// 2T-1 = 1023 relative positions

typedef __bf16 bf16x8 __attribute__((ext_vector_type(8)));
typedef float  f32x4  __attribute__((ext_vector_type(4)));

__device__ inline unsigned short f2b(float f) {       // f32 -> bf16 bits, RNE
  union { float f; unsigned u; } v; v.f = f;
  unsigned r = v.u + 0x7fff + ((v.u >> 16) & 1);
  return (unsigned short)(r >> 16);
}
__device__ inline float b2f(unsigned short u) {
  union { unsigned u; float f; } v; v.u = ((unsigned)u) << 16;
  return v.f;
}

// ---------------------------------------------------------------------------
// emb_rel[r][c]: hi bf16 [1023][256], lo bf16 [1023][256] (residual),
// transposed hi [256][1024] (pad col zeroed)
// ---------------------------------------------------------------------------
__global__ __launch_bounds__(256) void k_embrel(
    const float* __restrict__ teW, const float* __restrict__ teb,
    unsigned short* __restrict__ embB, unsigned short* __restrict__ embLo,
    unsigned short* __restrict__ embT)
{
  __shared__ float e[256];
  const int r = blockIdx.x;        // 0..1022
  const int tid = threadIdx.x;
  const float rel = (float)(r - (TS - 1));
  if (tid < 128) {
    float f = expf((float)tid * (-9.210340371976184f / 127.0f)); // -ln(1e4)/(half-1)
    float ang = rel * f;
    e[tid] = sinf(ang);
    e[tid + 128] = cosf(ang);
  }
  __syncthreads();
  float acc = teb[tid];
  for (int kk = 0; kk < 256; ++kk)
    acc = fmaf(e[kk], teW[kk * 256 + tid], acc);
  unsigned short hv = f2b(acc);
  embB[r * 256 + tid] = hv;
  embLo[r * 256 + tid] = f2b(acc - b2f(hv));
  embT[(size_t)tid * 1024 + r] = hv;
  if (r == 0) embT[(size_t)tid * 1024 + 1023] = 0;  // pad col: keep finite
}

// ---------------------------------------------------------------------------
// h [48,256,512] fp32  ->  hmB [24576][256] bf16   (hm[m,c] = h[b,c,t])
// ---------------------------------------------------------------------------
__global__ __launch_bounds__(256) void k_prep_h(
    const float* __restrict__ h, unsigned short* __restrict__ hmB)
{
  __shared__ float t[32 * 132];
  const int t0 = blockIdx.x * 128, c0 = blockIdx.y * 32, b = blockIdx.z;
  const int tid = threadIdx.x;
#pragma unroll
  for (int i = 0; i < 4; ++i) {
    int cl = i * 8 + (tid >> 5);           // 0..31
    int t4 = (tid & 31) * 4;               // 0..124
    float4 v = *(const float4*)&h[((size_t)b * 256 + c0 + cl) * 512 + t0 + t4];
    t[cl * 132 + t4 + 0] = v.x; t[cl * 132 + t4 + 1] = v.y;
    t[cl * 132 + t4 + 2] = v.z; t[cl * 132 + t4 + 3] = v.w;
  }
  __syncthreads();
#pragma unroll
  for (int i = 0; i < 16; ++i) {
    int tl = i * 8 + (tid >> 5);           // 0..127
    int cl = tid & 31;
    hmB[((size_t)b * 512 + t0 + tl) * 256 + c0 + cl] = f2b(t[cl * 132 + tl]);
  }
}

// ---------------------------------------------------------------------------
// Weights fp32 [K=256][N=256] -> bf16 transposed [N][K], 7 matrices
// ---------------------------------------------------------------------------
__global__ __launch_bounds__(256) void k_prep_w(
    const float* __restrict__ w0, const float* __restrict__ w1,
    const float* __restrict__ w2, const float* __restrict__ w3,
    const float* __restrict__ w4, const float* __restrict__ w5,
    const float* __restrict__ w6, unsigned short* __restrict__ WtB)
{
  __shared__ float t[64 * 68];
  const int mat = blockIdx.z;
  const float* W = (mat == 0) ? w0 : (mat == 1) ? w1 : (mat == 2) ? w2 :
                   (mat == 3) ? w3 : (mat == 4) ? w4 : (mat == 5) ? w5 : w6;
  unsigned short* dst = WtB + (size_t)mat * 65536;
  const int k0 = blockIdx.x * 64, n0 = blockIdx.y * 64;
  const int tid = threadIdx.x;
#pragma unroll
  for (int i = 0; i < 4; ++i) {
    int kr = i * 16 + (tid >> 4);          // 0..63 local k
    int nc = (tid & 15) * 4;               // 0..60 local n
    float4 v = *(const float4*)&W[(size_t)(k0 + kr) * 256 + n0 + nc];
    t[kr * 68 + nc + 0] = v.x; t[kr * 68 + nc + 1] = v.y;
    t[kr * 68 + nc + 2] = v.z; t[kr * 68 + nc + 3] = v.w;
  }
  __syncthreads();
#pragma unroll
  for (int i = 0; i < 4; ++i) {
    int nr = i * 16 + (tid >> 4);          // local n
    int kc = (tid & 15) * 4;               // local k
#pragma unroll
    for (int j = 0; j < 4; ++j)
      dst[(size_t)(n0 + nr) * 256 + k0 + kc + j] = f2b(t[(kc + j) * 68 + nr]);
  }
}

// ---------------------------------------------------------------------------
// V bf16 [24576][256] -> Vt bf16 [48][256][512]
// ---------------------------------------------------------------------------
__global__ __launch_bounds__(256) void k_prep_vt(
    const unsigned short* __restrict__ vB, unsigned short* __restrict__ vtB)
{
  __shared__ unsigned short tt[64][68];
  const int s0 = blockIdx.x * 64, h0 = blockIdx.y * 64, b = blockIdx.z;
  const int tid = threadIdx.x;
#pragma unroll
  for (int i = 0; i < 4; ++i) {
    int r = i * 16 + (tid >> 4);
    int c = (tid & 15) * 4;
    ushort4 v = *(const ushort4*)&vB[((size_t)(b * 512 + s0 + r) << 8) + h0 + c];
    tt[r][c + 0] = v.x; tt[r][c + 1] = v.y; tt[r][c + 2] = v.z; tt[r][c + 3] = v.w;
  }
  __syncthreads();
#pragma unroll
  for (int i = 0; i < 4; ++i) {
    int hr = i * 16 + (tid >> 4);
    int sc = (tid & 15) * 4;
    ushort4 o;
    o.x = tt[sc + 0][hr]; o.y = tt[sc + 1][hr];
    o.z = tt[sc + 2][hr]; o.w = tt[sc + 3][hr];
    *(ushort4*)&vtB[((size_t)(b * 256 + h0 + hr) << 9) + s0 + sc] = o;
  }
}

// ---------------------------------------------------------------------------
// bf16 MFMA GEMM: C[M,256] = act(A[M,256] @ Wt^T + bias)
// outB = bf16 hi, outL = bf16 lo residual (optional, for compensated logits)
// ---------------------------------------------------------------------------
template<int ACT>
__global__ __launch_bounds__(256) void k_gemm(
    const unsigned short* __restrict__ A, const unsigned short* __restrict__ Wt,
    const float* __restrict__ bias,
    float* __restrict__ outF, unsigned short* __restrict__ outB,
    unsigned short* __restrict__ outL)
{
  __shared__ uint4 As4[2048];   // 32 KB
  __shared__ uint4 Ws4[2048];   // 32 KB
  char* AsB = (char*)As4;
  char* WsB = (char*)Ws4;

  const int tid  = threadIdx.x;
  const int lane = tid & 63;
  const int w    = tid >> 6;
  const int wr   = w >> 1, wc = w & 1;
  const int rq   = lane & 15;
  const int kq   = lane >> 4;

  const int m0 = blockIdx.x * 128;
  const int n0 = blockIdx.y * 128;
  const char* Ag = (const char*)A  + (size_t)m0 * 512;
  const char* Wg = (const char*)Wt + (size_t)n0 * 512;

  f32x4 acc[4][4];
#pragma unroll
  for (int mi = 0; mi < 4; ++mi)
#pragma unroll
    for (int ni = 0; ni < 4; ++ni)
      acc[mi][ni] = (f32x4){0.f, 0.f, 0.f, 0.f};

  for (int kt = 0; kt < 2; ++kt) {
    __syncthreads();
#pragma unroll
    for (int i = 0; i < 8; ++i) {
      int c = i * 256 + tid;
      int row = c >> 4;
      int colb = (c & 15) * 16;
      int sw = colb ^ ((row & 7) << 4);
      *(uint4*)(AsB + row * 256 + sw) =
          *(const uint4*)(Ag + (size_t)row * 512 + kt * 256 + colb);
      *(uint4*)(WsB + row * 256 + sw) =
          *(const uint4*)(Wg + (size_t)row * 512 + kt * 256 + colb);
    }
    __syncthreads();

#pragma unroll
    for (int kk = 0; kk < 4; ++kk) {
      const int kb = kk * 64 + kq * 16;
      bf16x8 af[4], bfr[4];
#pragma unroll
      for (int mi = 0; mi < 4; ++mi) {
        int row = wr * 64 + mi * 16 + rq;
        af[mi] = *(const bf16x8*)(AsB + row * 256 + (kb ^ ((row & 7) << 4)));
      }
#pragma unroll
      for (int ni = 0; ni < 4; ++ni) {
        int row = wc * 64 + ni * 16 + rq;
        bfr[ni] = *(const bf16x8*)(WsB + row * 256 + (kb ^ ((row & 7) << 4)));
      }
#pragma unroll
      for (int mi = 0; mi < 4; ++mi)
#pragma unroll
        for (int ni = 0; ni < 4; ++ni)
          acc[mi][ni] = __builtin_amdgcn_mfma_f32_16x16x32_bf16(
              af[mi], bfr[ni], acc[mi][ni], 0, 0, 0);
    }
  }

  float bv[4];
#pragma unroll
  for (int ni = 0; ni < 4; ++ni)
    bv[ni] = bias[n0 + wc * 64 + ni * 16 + rq];

#pragma unroll
  for (int mi = 0; mi < 4; ++mi) {
#pragma unroll
    for (int ni = 0; ni < 4; ++ni) {
      const int n = n0 + wc * 64 + ni * 16 + rq;
#pragma unroll
      for (int j = 0; j < 4; ++j) {
        const int m = m0 + wr * 64 + mi * 16 + kq * 4 + j;
        float vl = acc[mi][ni][j] + bv[ni];
        if (ACT) vl = vl / (1.0f + __expf(-vl));
        if (outF) outF[(size_t)m * 256 + n] = vl;
        if (outB) {
          unsigned short hv = f2b(vl);
          outB[(size_t)m * 256 + n] = hv;
          if (outL) outL[(size_t)m * 256 + n] = f2b(vl - b2f(hv));
        }
      }
    }
  }
}

// ---------------------------------------------------------------------------
// vx[m] = hidX[m,:] (bf16) @ xW2 + xb2
// ---------------------------------------------------------------------------
__global__ __launch_bounds__(256) void k_vx2(
    const unsigned short* __restrict__ hid,
    const float* __restrict__ xW2, const float* __restrict__ xb2,
    float* __restrict__ vx)
{
  const int m0 = blockIdx.x * 32;
  const int tid = threadIdx.x;
  const int tr = tid >> 3, tc = tid & 7;
  const unsigned short* row = hid + (size_t)(m0 + tr) * 256 + tc * 32;
  float acc = 0.0f;
#pragma unroll
  for (int i = 0; i < 4; ++i) {
    uint4 r = *(const uint4*)&row[i * 8];
    const unsigned rr[4] = {r.x, r.y, r.z, r.w};
#pragma unroll
    for (int jj = 0; jj < 4; ++jj) {
      float lo = b2f((unsigned short)(rr[jj] & 0xffff));
      float hi = b2f((unsigned short)(rr[jj] >> 16));
      acc = fmaf(lo, xW2[tc * 32 + i * 8 + 2 * jj + 0], acc);
      acc = fmaf(hi, xW2[tc * 32 + i * 8 + 2 * jj + 1], acc);
    }
  }
  acc += __shfl_xor(acc, 1);
  acc += __shfl_xor(acc, 2);
  acc += __shfl_xor(acc, 4);
  if (tc == 0) vx[m0 + tr] = acc + xb2[0];
}

// ---------------------------------------------------------------------------
// MFMA fused attention. Block = (b, 16 t-rows), 4 waves, 256 threads.
//  phase1: S = Q@K^T + gather(R = Q@embband^T), hi/lo-compensated bf16
//  softmax fp32 in regs (+ x-update), P -> Pb[16][520] and banded Pe[16][544]
//  phase2: O = P@Vt + Pe@embT-band               [waves split h: 64 each]
// LDS: S[16][524]f32 | union{ Rl[4][16][132]f32 , Pb+Pe } | sml[16]
// Rl stores the per-row RELATIVE band window: Rl[t'][r_local - t'], since
// only r_local in [t', t'+127] is gathered by row t' (rel = 127 - slw).
// ---------------------------------------------------------------------------
#define RLS 132
__global__ __launch_bounds__(256, 2) void k_attn2(
    const float* __restrict__ xin, const float* __restrict__ hin,
    const unsigned short* __restrict__ qB, const unsigned short* __restrict__ qLo,
    const unsigned short* __restrict__ kB, const unsigned short* __restrict__ kLo,
    const unsigned short* __restrict__ vtB, const float* __restrict__ vxm,
    const unsigned short* __restrict__ embB, const unsigned short* __restrict__ embLo,
    const unsigned short* __restrict__ embT,
    float* __restrict__ xout, float* __restrict__ hout)
{
  __shared__ char smem[67648];
  float* S  = (float*)smem;                                      // [16][524]
  float* Rl0 = (float*)(smem + 33536);                           // [4][16][132]
  unsigned short* Pb = (unsigned short*)(smem + 33536);          // [16][520]
  unsigned short* Pe = (unsigned short*)(smem + 33536 + 16640);  // [16][544]
  float* sml = (float*)(smem + 33536 + 34048);                   // [16]

  const int tid  = threadIdx.x;
  const int lane = tid & 63;
  const int w    = tid >> 6;
  const int rq   = lane & 15;
  const int kq   = lane >> 4;
  const int t0   = blockIdx.x * 16;
  const int b    = blockIdx.y;
  const int sw   = w * 128;        // this wave's s-offset (phase 1)

  // ---- Q fragments hi+lo (held through phase 1) ----
  bf16x8 qh[8], ql[8];
  {
    const size_t qoff = ((size_t)(b * TS + t0 + rq) << 8) + kq * 8;
#pragma unroll
    for (int ks = 0; ks < 8; ++ks) {
      qh[ks] = *(const bf16x8*)(qB  + qoff + ks * 32);
      ql[ks] = *(const bf16x8*)(qLo + qoff + ks * 32);
    }
  }

  // ---- phase 1a: QK^T for s in [sw, sw+128), 3-term compensated ----
  f32x4 acc[8];
#pragma unroll
  for (int ni = 0; ni < 8; ++ni) acc[ni] = (f32x4){0.f, 0.f, 0.f, 0.f};
  {
    const size_t koff = ((size_t)(b * TS + sw + rq) << 8) + kq * 8;
    const unsigned short* kp  = kB  + koff;
    const unsigned short* kpl = kLo + koff;
#pragma unroll
    for (int ks = 0; ks < 8; ++ks) {
#pragma unroll
      for (int ni = 0; ni < 8; ++ni) {
        bf16x8 kh = *(const bf16x8*)(kp  + ni * 4096 + ks * 32);
        bf16x8 kl = *(const bf16x8*)(kpl + ni * 4096 + ks * 32);
        acc[ni] = __builtin_amdgcn_mfma_f32_16x16x32_bf16(qh[ks], kh, acc[ni], 0, 0, 0);
        acc[ni] = __builtin_amdgcn_mfma_f32_16x16x32_bf16(ql[ks], kh, acc[ni], 0, 0, 0);
        acc[ni] = __builtin_amdgcn_mfma_f32_16x16x32_bf16(qh[ks], kl, acc[ni], 0, 0, 0);
      }
    }
  }

  // ---- phase 1b: R[t'][r_local] = Q . embband^T  (143-wide band, 9 frags)
  f32x4 racc[9];
#pragma unroll
  for (int ni = 0; ni < 9; ++ni) racc[ni] = (f32x4){0.f, 0.f, 0.f, 0.f};
  const int rbR = t0 - sw + 384;            // r_global = rbR + r_local
  {
    const unsigned short *ep[9], *epl[9];
#pragma unroll
    for (int ni = 0; ni < 9; ++ni) {
      int rr = rbR + ni * 16 + rq;
      if (rr > 1022) rr = 1022;             // only r_local=143 (never gathered)
      ep[ni]  = embB  + ((size_t)rr << 8) + kq * 8;
      epl[ni] = embLo + ((size_t)rr << 8) + kq * 8;
    }
#pragma unroll
    for (int ks = 0; ks < 8; ++ks) {
#pragma unroll
      for (int ni = 0; ni < 9; ++ni) {
        bf16x8 eh = *(const bf16x8*)(ep[ni]  + ks * 32);
        bf16x8 el = *(const bf16x8*)(epl[ni] + ks * 32);
        racc[ni] = __builtin_amdgcn_mfma_f32_16x16x32_bf16(qh[ks], eh, racc[ni], 0, 0, 0);
        racc[ni] = __builtin_amdgcn_mfma_f32_16x16x32_bf16(ql[ks], eh, racc[ni], 0, 0, 0);
        racc[ni] = __builtin_amdgcn_mfma_f32_16x16x32_bf16(qh[ks], el, racc[ni], 0, 0, 0);
      }
    }
  }

  // ---- R to LDS (wave-private, relative window), gather, assemble S ----
  {
    float* Rl = Rl0 + w * (16 * RLS);
#pragma unroll
    for (int ni = 0; ni < 9; ++ni)
#pragma unroll
      for (int j = 0; j < 4; ++j) {
        int tp  = kq * 4 + j;                // S row t'
        int rel = ni * 16 + rq - tp;         // r_local - t'
        if (rel >= 0 && rel < 128)
          Rl[tp * RLS + rel] = racc[ni][j];
      }
#pragma unroll
    for (int ni = 0; ni < 8; ++ni)
#pragma unroll
      for (int j = 0; j < 4; ++j) {
        int tp  = kq * 4 + j;
        int slw = ni * 16 + rq;
        // needed r_local = tp - slw + 127  ->  rel = 127 - slw
        S[tp * 524 + sw + slw] = acc[ni][j] + Rl[tp * RLS + (127 - slw)];
      }
  }
  __syncthreads();   // B1: S complete, R dead

  // ---- softmax (16 threads per row) + x-update; zero Pe (aliases Rl) ----
  const int row = tid >> 4, tx = tid & 15;
  {
    unsigned int* pz = (unsigned int*)Pe;
#pragma unroll
    for (int i = 0; i < 17; ++i) pz[i * 256 + tid] = 0u;
  }
  float p[32];
  float mx = -3.0e38f, l = 0.f;
  {
    const float* Srow = S + row * 524 + tx * 4;
#pragma unroll
    for (int i = 0; i < 8; ++i) {
      float4 v = *(const float4*)(Srow + i * 64);
      p[4*i+0] = v.x; p[4*i+1] = v.y; p[4*i+2] = v.z; p[4*i+3] = v.w;
    }
#pragma unroll
    for (int i = 0; i < 32; ++i) mx = fmaxf(mx, p[i]);
    mx = fmaxf(mx, __shfl_xor(mx, 1)); mx = fmaxf(mx, __shfl_xor(mx, 2));
    mx = fmaxf(mx, __shfl_xor(mx, 4)); mx = fmaxf(mx, __shfl_xor(mx, 8));
#pragma unroll
    for (int i = 0; i < 32; ++i) { p[i] = __expf(p[i] - mx); l += p[i]; }
    l += __shfl_xor(l, 1); l += __shfl_xor(l, 2);
    l += __shfl_xor(l, 4); l += __shfl_xor(l, 8);
  }
  const float invl = 1.0f / l;
  {
    const float* vxp = vxm + b * TS;
    const float* xp  = xin + (size_t)b * 3 * TS;
    float wsum = 0.f, xa0 = 0.f, xa1 = 0.f, xa2 = 0.f;
#pragma unroll
    for (int i = 0; i < 8; ++i) {
      int s = i * 64 + tx * 4;
      float4 vv = *(const float4*)(vxp + s);
      float4 x0 = *(const float4*)(xp + s);
      float4 x1 = *(const float4*)(xp + TS + s);
      float4 x2 = *(const float4*)(xp + 2 * TS + s);
      float wv;
      wv = p[4*i+0] * vv.x; wsum += wv; xa0 = fmaf(wv, x0.x, xa0); xa1 = fmaf(wv, x1.x, xa1); xa2 = fmaf(wv, x2.x, xa2);
      wv = p[4*i+1] * vv.y; wsum += wv; xa0 = fmaf(wv, x0.y, xa0); xa1 = fmaf(wv, x1.y, xa1); xa2 = fmaf(wv, x2.y, xa2);
      wv = p[4*i+2] * vv.z; wsum += wv; xa0 = fmaf(wv, x0.z, xa0); xa1 = fmaf(wv, x1.z, xa1); xa2 = fmaf(wv, x2.z, xa2);
      wv = p[4*i+3] * vv.w; wsum += wv; xa0 = fmaf(wv, x0.w, xa0); xa1 = fmaf(wv, x1.w, xa1); xa2 = fmaf(wv, x2.w, xa2);
    }
    wsum += __shfl_xor(wsum, 1); wsum += __shfl_xor(wsum, 2);
    wsum += __shfl_xor(wsum, 4); wsum += __shfl_xor(wsum, 8);
    xa0 += __shfl_xor(xa0, 1); xa0 += __shfl_xor(xa0, 2); xa0 += __shfl_xor(xa0, 4); xa0 += __shfl_xor(xa0, 8);
    xa1 += __shfl_xor(xa1, 1); xa1 += __shfl_xor(xa1, 2); xa1 += __shfl_xor(xa1, 4); xa1 += __shfl_xor(xa1, 8);
    xa2 += __shfl_xor(xa2, 1); xa2 += __shfl_xor(xa2, 2); xa2 += __shfl_xor(xa2, 4); xa2 += __shfl_xor(xa2, 8);
    if (tx == 0) {
      int t = t0 + row;
      float ws = wsum * invl;
      xout[(b * 3 + 0) * TS + t] = xp[t]           * (1.0f + ws) - xa0 * invl;
      xout[(b * 3 + 1) * TS + t] = xp[TS + t]      * (1.0f + ws) - xa1 * invl;
      xout[(b * 3 + 2) * TS + t] = xp[2 * TS + t]  * (1.0f + ws) - xa2 * invl;
      sml[row] = invl;
    }
  }
  __syncthreads();   // B2: Pe zeroed everywhere before scatter

  // ---- scatter P -> Pb (row-major) and Pe (banded: r = row+511-s) ----
  {
    unsigned short* pbrow = Pb + row * 520 + tx * 4;
    unsigned short* perow = Pe + row * 544 + row + 511;
#pragma unroll
    for (int i = 0; i < 8; ++i) {
      int s = i * 64 + tx * 4;
      ushort4 pu;
      pu.x = f2b(p[4*i+0]); pu.y = f2b(p[4*i+1]);
      pu.z = f2b(p[4*i+2]); pu.w = f2b(p[4*i+3]);
      *(ushort4*)(pbrow + i * 64) = pu;
      perow[-(s + 0)] = pu.x; perow[-(s + 1)] = pu.y;
      perow[-(s + 2)] = pu.z; perow[-(s + 3)] = pu.w;
    }
  }
  __syncthreads();   // B3: Pb/Pe/sml ready

  // ---- phase 2: O[t'][h] = P@Vt + Pe@embT-band, h-slice per wave ----
  const int n0 = w * 64;
  f32x4 oacc[4];
#pragma unroll
  for (int ni = 0; ni < 4; ++ni) oacc[ni] = (f32x4){0.f, 0.f, 0.f, 0.f};
  {
    const unsigned short* pbp = Pb + rq * 520 + kq * 8;
    const unsigned short* vtp = vtB + ((size_t)(b * 256 + n0 + rq) << 9) + kq * 8;
#pragma unroll
    for (int ks = 0; ks < 16; ++ks) {
      bf16x8 pa = *(const bf16x8*)(pbp + ks * 32);
      bf16x8 vf[4];
#pragma unroll
      for (int ni = 0; ni < 4; ++ni) vf[ni] = *(const bf16x8*)(vtp + ni * 8192 + ks * 32);
#pragma unroll
      for (int ni = 0; ni < 4; ++ni)
        oacc[ni] = __builtin_amdgcn_mfma_f32_16x16x32_bf16(pa, vf[ni], oacc[ni], 0, 0, 0);
    }
  }
  {
    const unsigned short* pep = Pe + rq * 544 + kq * 8;
    const unsigned short* etp = embT + ((size_t)(n0 + rq) << 10);
#pragma unroll
    for (int ks = 0; ks < 17; ++ks) {
      bf16x8 pa = *(const bf16x8*)(pep + ks * 32);
      int rg = t0 + ks * 32 + kq * 8;            // r_global = t0 + r_local
      if (rg > 1016) rg = 1016;                  // clamp (Pe zero there)
      bf16x8 ef[4];
#pragma unroll
      for (int ni = 0; ni < 4; ++ni) ef[ni] = *(const bf16x8*)(etp + (ni << 14) + rg);
#pragma unroll
      for (int ni = 0; ni < 4; ++ni)
        oacc[ni] = __builtin_amdgcn_mfma_f32_16x16x32_bf16(pa, ef[ni], oacc[ni], 0, 0, 0);
    }
  }

  // ---- epilogue: normalize by 1/l, add h residual, coalesced float4 ----
  {
    float il0 = sml[kq * 4 + 0], il1 = sml[kq * 4 + 1];
    float il2 = sml[kq * 4 + 2], il3 = sml[kq * 4 + 3];
#pragma unroll
    for (int ni = 0; ni < 4; ++ni) {
      int hh = n0 + ni * 16 + rq;
      size_t off = (((size_t)(b * 256 + hh)) << 9) + t0 + kq * 4;
      float4 hv = *(const float4*)(hin + off);
      float4 ov;
      ov.x = hv.x + oacc[ni][0] * il0;
      ov.y = hv.y + oacc[ni][1] * il1;
      ov.z = hv.z + oacc[ni][2] * il2;
      ov.w = hv.w + oacc[ni][3] * il3;
      *(float4*)(hout + off) = ov;
    }
  }
}

// ---------------------------------------------------------------------------
extern "C" void kernel_launch(void* const* d_in, const int* in_sizes, int n_in,
                              void* d_out, int out_size, void* d_ws, size_t ws_size,
                              hipStream_t stream)
{
  const float* x   = (const float*)d_in[0];
  const float* h   = (const float*)d_in[1];
  const float* qW1 = (const float*)d_in[2];
  const float* qb1 = (const float*)d_in[3];
  const float* qW2 = (const float*)d_in[4];
  const float* qb2 = (const float*)d_in[5];
  const float* kW1 = (const float*)d_in[6];
  const float* kb1 = (const float*)d_in[7];
  const float* kW2 = (const float*)d_in[8];
  const float* kb2 = (const float*)d_in[9];
  const float* vW1 = (const float*)d_in[10];
  const float* vb1 = (const float*)d_in[11];
  const float* vW2 = (const float*)d_in[12];
  const float* vb2 = (const float*)d_in[13];
  const float* xW1 = (const float*)d_in[14];
  const float* xb1 = (const float*)d_in[15];
  const float* xW2 = (const float*)d_in[16];
  const float* xb2 = (const float*)d_in[17];
  const float* teW = (const float*)d_in[18];
  const float* teb = (const float*)d_in[19];

  // ws layout (all bf16 except vx) ~103 MB
  unsigned short* cur = (unsigned short*)d_ws;
  unsigned short* embB  = cur; cur += 1023 * 256;
  unsigned short* embLo = cur; cur += 1023 * 256;
  unsigned short* embT  = cur; cur += 256 * 1024;
  unsigned short* hmB   = cur; cur += (size_t)24576 * 256;
  unsigned short* WtB   = cur; cur += 7 * 65536;
  unsigned short* hid   = cur; cur += (size_t)24576 * 256;
  unsigned short* qBp   = cur; cur += (size_t)24576 * 256;
  unsigned short* qLo   = cur; cur += (size_t)24576 * 256;
  unsigned short* kBp   = cur; cur += (size_t)24576 * 256;
  unsigned short* kLo   = cur; cur += (size_t)24576 * 256;
  unsigned short* vBp   = cur; cur += (size_t)24576 * 256;
  unsigned short* vtB   = cur; cur += (size_t)24576 * 256;
  float* vx = (float*)cur;                                // 24576 f32

  float* xout = (float*)d_out;                // [48,3,512]
  float* hout = xout + NB * 3 * TS;           // [48,256,512]

  k_embrel<<<1023, 256, 0, stream>>>(teW, teb, embB, embLo, embT);
  k_prep_h<<<dim3(4, 8, 48), 256, 0, stream>>>(h, hmB);
  k_prep_w<<<dim3(4, 4, 7), 256, 0, stream>>>(qW1, qW2, kW1, kW2, vW1, vW2, xW1, WtB);

  const dim3 gg(192, 2);
  k_gemm<1><<<gg, 256, 0, stream>>>(hmB, WtB + 0 * 65536, qb1, nullptr, hid, nullptr);
  k_gemm<0><<<gg, 256, 0, stream>>>(hid, WtB + 1 * 65536, qb2, nullptr, qBp, qLo);
  k_gemm<1><<<gg, 256, 0, stream>>>(hmB, WtB + 2 * 65536, kb1, nullptr, hid, nullptr);
  k_gemm<0><<<gg, 256, 0, stream>>>(hid, WtB + 3 * 65536, kb2, nullptr, kBp, kLo);
  k_gemm<1><<<gg, 256, 0, stream>>>(hmB, WtB + 4 * 65536, vb1, nullptr, hid, nullptr);
  k_gemm<0><<<gg, 256, 0, stream>>>(hid, WtB + 5 * 65536, vb2, nullptr, vBp, nullptr);
  k_gemm<1><<<gg, 256, 0, stream>>>(vBp, WtB + 6 * 65536, xb1, nullptr, hid, nullptr);
  k_vx2<<<768, 256, 0, stream>>>(hid, xW2, xb2, vx);
  k_prep_vt<<<dim3(8, 4, 48), 256, 0, stream>>>(vBp, vtB);

  k_attn2<<<dim3(32, 48), 256, 0, stream>>>(x, h, qBp, qLo, kBp, kLo, vtB, vx,
                                            embB, embLo, embT, xout, hout);
}